// Round 1
// baseline (562.624 us; speedup 1.0000x reference)
//
#include <hip/hip_runtime.h>

// Problem constants (fixed by setup_inputs)
constexpr int BB = 16;         // batch
constexpr int SS = 4096;       // seq
constexpr int DD = 1024;       // hidden dim
constexpr int KK = 65536;      // num keys
constexpr int GM = BB * SS;    // GEMM M = 65536
constexpr int GK = DD;         // GEMM K = 1024

typedef __attribute__((ext_vector_type(8))) short bf16x8;
typedef __attribute__((ext_vector_type(4))) float f32x4;
typedef __attribute__((ext_vector_type(8))) unsigned short ushort8;

#define GLD_LDS16(g, l)                                                        \
  __builtin_amdgcn_global_load_lds(                                            \
      (const __attribute__((address_space(1))) void*)(g),                      \
      (__attribute__((address_space(3))) void*)(l), 16, 0, 0)

__device__ __forceinline__ unsigned short f2bf(float x) {
  unsigned u = __float_as_uint(x);
  u += 0x7fffu + ((u >> 16) & 1u);   // RNE
  return (unsigned short)(u >> 16);
}

// ---------------- fp32 -> bf16 conversion (8 elems/thread/iter) -------------
__global__ void cvt_bf16(const float* __restrict__ in,
                         unsigned short* __restrict__ out, int n8) {
  int stride = gridDim.x * blockDim.x;
  for (int i = blockIdx.x * blockDim.x + threadIdx.x; i < n8; i += stride) {
    const float4* p = (const float4*)in + (size_t)i * 2;
    float4 a = p[0], b = p[1];
    ushort8 r;
    r[0] = f2bf(a.x); r[1] = f2bf(a.y); r[2] = f2bf(a.z); r[3] = f2bf(a.w);
    r[4] = f2bf(b.x); r[5] = f2bf(b.y); r[6] = f2bf(b.z); r[7] = f2bf(b.w);
    *(ushort8*)(out + (size_t)i * 8) = r;
  }
}

// ---------------- GEMM: C[m,n] = sum_k A[m,k]*W[n,k] + bias[n] --------------
// m97 structure: 128x128 tile, BK=32, 4 waves (2x2), global_load_lds w=16,
// 16x16x32 bf16 MFMA, single-buffer 2-barrier K-loop, XCD-swizzled blockIdx.
// Output written to d_out with per-batch row offset (row stride S+1=4097).
__global__ __launch_bounds__(256) void gemm_bt(
    const unsigned short* __restrict__ A,   // GM x GK bf16
    const unsigned short* __restrict__ Bm,  // DD x GK bf16 (W, row-major)
    const float* __restrict__ bias,         // DD fp32
    float* __restrict__ out) {
  __shared__ unsigned short sA[128 * 32];
  __shared__ unsigned short sB[128 * 32];

  // bijective XCD swizzle: 4096 wgs, 8 XCDs -> each XCD gets contiguous 512
  int g = blockIdx.x;
  int t = ((g & 7) << 9) + (g >> 3);
  int mt = t >> 3, nt = t & 7;            // 512 M-tiles x 8 N-tiles
  int m0 = mt << 7, n0 = nt << 7;

  int tid = threadIdx.x, lane = tid & 63, wv = tid >> 6;
  int wr = wv >> 1, wc = wv & 1;          // wave 2x2 grid, each owns 64x64
  int fr = lane & 15, ko = (lane >> 4) << 3;

  f32x4 acc[4][4] = {};

  // staging geometry: byte off in 8KB tile = wv*2048 + i*1024 + lane*16
  int srow[2], scol[2];
  for (int i = 0; i < 2; ++i) {
    int off = (wv << 11) + (i << 10) + (lane << 4);
    srow[i] = off >> 6;           // 64B per row (32 bf16)
    scol[i] = (off & 63) >> 1;    // element col within row
  }

  for (int kt = 0; kt < GK / 32; ++kt) {
    int k0 = kt << 5;
    // stage A & B tiles (each wave: 2x1KB per tile, LDS dest = uniform base)
    for (int i = 0; i < 2; ++i) {
      unsigned short* ldsA = sA + (wv << 10) + (i << 9);
      unsigned short* ldsB = sB + (wv << 10) + (i << 9);
      GLD_LDS16(A + (size_t)(m0 + srow[i]) * GK + k0 + scol[i], ldsA);
      GLD_LDS16(Bm + (size_t)(n0 + srow[i]) * GK + k0 + scol[i], ldsB);
    }
    __syncthreads();   // compiler drains vmcnt before barrier

    bf16x8 af[4], bfr[4];
#pragma unroll
    for (int i = 0; i < 4; ++i) {
      af[i]  = *(const bf16x8*)&sA[((wr << 6) + (i << 4) + fr) * 32 + ko];
      bfr[i] = *(const bf16x8*)&sB[((wc << 6) + (i << 4) + fr) * 32 + ko];
    }
#pragma unroll
    for (int m = 0; m < 4; ++m)
#pragma unroll
      for (int n = 0; n < 4; ++n)
        acc[m][n] = __builtin_amdgcn_mfma_f32_16x16x32_bf16(af[m], bfr[n],
                                                            acc[m][n], 0, 0, 0);
    __syncthreads();   // reads done before next stage overwrites
  }

  // epilogue: C/D layout col=lane&15, row=(lane>>4)*4+j  [m89-verified]
  int r0 = (lane >> 4) << 2, c = lane & 15;
#pragma unroll
  for (int n = 0; n < 4; ++n) {
    int gcol = n0 + (wc << 6) + (n << 4) + c;
    float bv = bias[gcol];
#pragma unroll
    for (int m = 0; m < 4; ++m) {
      int gr = m0 + (wr << 6) + (m << 4) + r0;
#pragma unroll
      for (int j = 0; j < 4; ++j) {
        int grow = gr + j;                       // m index = b*4096 + s
        size_t o = ((size_t)(grow + (grow >> 12)) << 10) + gcol;
        out[o] = acc[m][n][j] + bv;
      }
    }
  }
}

// ---------------- cos similarity partial argmax ------------------------------
// block = 1024 threads = 16 waves; wave w owns batch w. Key staged in LDS
// (double-buffered, T14 issue-early/write-late). fp32 throughout.
__global__ __launch_bounds__(1024) void cos_partial(
    const float* __restrict__ q,      // BB x DD (concept_signal)
    const float* __restrict__ keys,   // KK x DD
    float* __restrict__ pscore, int* __restrict__ pidx, int kpb) {
  __shared__ float kb[2][DD];
  int tid = threadIdx.x, lane = tid & 63, w = tid >> 6;
  int k0 = blockIdx.x * kpb;

  // q fragment: lane holds elements [lane*16, lane*16+16)
  float4 q4[4];
  const float4* qrow = (const float4*)(q + (size_t)w * DD);
#pragma unroll
  for (int i = 0; i < 4; ++i) q4[i] = qrow[(lane << 2) + i];

  kb[0][tid] = keys[(size_t)k0 * DD + tid];
  __syncthreads();

  float best = -1e30f;
  int bidx = 0;
  for (int t = 0; t < kpb; ++t) {
    int cur = t & 1;
    float nxt = 0.f;
    if (t + 1 < kpb) nxt = keys[(size_t)(k0 + t + 1) * DD + tid];  // issue early

    float dot = 0.f, nrm = 0.f;
    const float4* kr = (const float4*)kb[cur];
#pragma unroll
    for (int i = 0; i < 4; ++i) {
      float4 kv = kr[(lane << 2) + i];
      float4 qv = q4[i];
      dot += kv.x * qv.x + kv.y * qv.y + kv.z * qv.z + kv.w * qv.w;
      nrm += kv.x * kv.x + kv.y * kv.y + kv.z * kv.z + kv.w * kv.w;
    }
#pragma unroll
    for (int off = 32; off; off >>= 1) {
      dot += __shfl_xor(dot, off);
      nrm += __shfl_xor(nrm, off);
    }
    if (lane == 0) {
      float s = dot * rsqrtf(fmaxf(nrm, 1e-24f));  // argmax(cos) == argmin(dist)
      if (s > best) { best = s; bidx = k0 + t; }   // strict > keeps first index
    }
    if (t + 1 < kpb) kb[cur ^ 1][tid] = nxt;       // write late (vmcnt hidden)
    __syncthreads();
  }
  if (lane == 0) {
    pscore[(size_t)w * gridDim.x + blockIdx.x] = best;
    pidx[(size_t)w * gridDim.x + blockIdx.x] = bidx;
  }
}

// ---------------- final argmax reduce + token gather + l2norm ---------------
__global__ __launch_bounds__(256) void select_write(
    const float* __restrict__ pscore, const int* __restrict__ pidx, int nb,
    const int* __restrict__ ktv, const float* __restrict__ values,
    float* __restrict__ out) {
  __shared__ float ss[4];
  __shared__ int si[4];
  __shared__ float snrm;
  __shared__ int swin;
  int b = blockIdx.x, tid = threadIdx.x, lane = tid & 63, wv = tid >> 6;

  float best = -1e30f;
  int bidx = 0x7fffffff;
  for (int t = tid; t < nb; t += 256) {
    float s = pscore[(size_t)b * nb + t];
    int i = pidx[(size_t)b * nb + t];
    if (s > best || (s == best && i < bidx)) { best = s; bidx = i; }
  }
#pragma unroll
  for (int off = 32; off; off >>= 1) {
    float s = __shfl_xor(best, off);
    int i = __shfl_xor(bidx, off);
    if (s > best || (s == best && i < bidx)) { best = s; bidx = i; }
  }
  if (lane == 0) { ss[wv] = best; si[wv] = bidx; }
  __syncthreads();
  if (tid == 0) {
    float bs = ss[0]; int bi = si[0];
    for (int w2 = 1; w2 < 4; ++w2)
      if (ss[w2] > bs || (ss[w2] == bs && si[w2] < bi)) { bs = ss[w2]; bi = si[w2]; }
    swin = ktv[bi];   // key_to_value mapping
  }
  __syncthreads();
  int idx = swin;

  float4 v = ((const float4*)(values + (size_t)idx * DD))[tid];
  float nrm = v.x * v.x + v.y * v.y + v.z * v.z + v.w * v.w;
#pragma unroll
  for (int off = 32; off; off >>= 1) nrm += __shfl_xor(nrm, off);
  if (lane == 0) ss[wv] = nrm;
  __syncthreads();
  if (tid == 0) snrm = rsqrtf(fmaxf(ss[0] + ss[1] + ss[2] + ss[3], 1e-24f));
  __syncthreads();
  float inv = snrm;

  float4 o;
  o.x = v.x * inv; o.y = v.y * inv; o.z = v.z * inv; o.w = v.w * inv;
  ((float4*)(out + (((size_t)b * (SS + 1) + SS) << 10)))[tid] = o;
}

// ---------------- launcher ---------------------------------------------------
extern "C" void kernel_launch(void* const* d_in, const int* in_sizes, int n_in,
                              void* d_out, int out_size, void* d_ws,
                              size_t ws_size, hipStream_t stream) {
  const float* hidden = (const float*)d_in[0];
  const float* csig   = (const float*)d_in[1];
  const float* keys   = (const float*)d_in[2];
  const float* values = (const float*)d_in[3];
  const int*   ktv    = (const int*)d_in[4];
  const float* W      = (const float*)d_in[5];
  const float* bias   = (const float*)d_in[6];
  float* out = (float*)d_out;

  char* ws = (char*)d_ws;
  unsigned short* hbf = (unsigned short*)ws;                       // 128 MB
  unsigned short* wbf = (unsigned short*)(ws + (size_t)GM * GK * 2);  // 2 MB
  float* pscore = (float*)(ws + (size_t)GM * GK * 2 + (size_t)DD * GK * 2);
  int* pidx = (int*)((char*)pscore + (size_t)BB * 512 * sizeof(float));

  // 1) convert hidden & W to bf16
  cvt_bf16<<<4096, 256, 0, stream>>>(hidden, hbf, GM * GK / 8);
  cvt_bf16<<<512, 256, 0, stream>>>(W, wbf, DD * GK / 8);

  // 2) cos-similarity partial argmax (independent of GEMM)
  cos_partial<<<512, 1024, 0, stream>>>(csig, keys, pscore, pidx, KK / 512);

  // 3) GEMM + bias into out rows s<4096
  gemm_bt<<<(GM / 128) * (DD / 128), 256, 0, stream>>>(hbf, wbf, bias, out);

  // 4) final reduce + token row s=4096
  select_write<<<BB, 256, 0, stream>>>(pscore, pidx, 512, ktv, values, out);
}

// Round 2
// 464.932 us; speedup vs baseline: 1.2101x; 1.2101x over previous
//
#include <hip/hip_runtime.h>

// Problem constants (fixed by setup_inputs)
constexpr int BB = 16;         // batch
constexpr int SS = 4096;       // seq
constexpr int DD = 1024;       // hidden dim
constexpr int KK = 65536;      // num keys
constexpr int GM = BB * SS;    // GEMM M = 65536
constexpr int GK = DD;         // GEMM K = 1024

typedef __attribute__((ext_vector_type(8))) short bf16x8;
typedef __attribute__((ext_vector_type(4))) float f32x4;
typedef __attribute__((ext_vector_type(8))) unsigned short ushort8;

#define GLD_LDS16(g, l)                                                        \
  __builtin_amdgcn_global_load_lds(                                            \
      (const __attribute__((address_space(1))) void*)(g),                      \
      (__attribute__((address_space(3))) void*)(l), 16, 0, 0)

__device__ __forceinline__ unsigned short f2bf(float x) {
  unsigned u = __float_as_uint(x);
  u += 0x7fffu + ((u >> 16) & 1u);   // RNE
  return (unsigned short)(u >> 16);
}

// ---------------- fp32 -> bf16 conversion (8 elems/thread/iter) -------------
__global__ void cvt_bf16(const float* __restrict__ in,
                         unsigned short* __restrict__ out, int n8) {
  int stride = gridDim.x * blockDim.x;
  for (int i = blockIdx.x * blockDim.x + threadIdx.x; i < n8; i += stride) {
    const float4* p = (const float4*)in + (size_t)i * 2;
    float4 a = p[0], b = p[1];
    ushort8 r;
    r[0] = f2bf(a.x); r[1] = f2bf(a.y); r[2] = f2bf(a.z); r[3] = f2bf(a.w);
    r[4] = f2bf(b.x); r[5] = f2bf(b.y); r[6] = f2bf(b.z); r[7] = f2bf(b.w);
    *(ushort8*)(out + (size_t)i * 8) = r;
  }
}

// ---------------- q transpose: csig[16][1024] -> qT[1024][16] ---------------
__global__ __launch_bounds__(256) void qt_prep(const float* __restrict__ csig,
                                               float* __restrict__ qT) {
  int e = blockIdx.x * 256 + threadIdx.x;   // 64 blocks cover 16384
  int b = e >> 10, d = e & 1023;
  qT[d * 16 + b] = csig[e];
}

// ---------------- GEMM: C[m,n] = sum_k A[m,k]*W[n,k] + bias[n] --------------
// m97 structure: 128x128 tile, BK=32, 4 waves (2x2), global_load_lds w=16,
// 16x16x32 bf16 MFMA, single-buffer 2-barrier K-loop, XCD-swizzled blockIdx.
__global__ __launch_bounds__(256) void gemm_bt(
    const unsigned short* __restrict__ A,   // GM x GK bf16
    const unsigned short* __restrict__ Bm,  // DD x GK bf16 (W, row-major)
    const float* __restrict__ bias,         // DD fp32
    float* __restrict__ out) {
  __shared__ unsigned short sA[128 * 32];
  __shared__ unsigned short sB[128 * 32];

  // bijective XCD swizzle: 4096 wgs, 8 XCDs -> each XCD gets contiguous 512
  int g = blockIdx.x;
  int t = ((g & 7) << 9) + (g >> 3);
  int mt = t >> 3, nt = t & 7;            // 512 M-tiles x 8 N-tiles
  int m0 = mt << 7, n0 = nt << 7;

  int tid = threadIdx.x, lane = tid & 63, wv = tid >> 6;
  int wr = wv >> 1, wc = wv & 1;          // wave 2x2 grid, each owns 64x64
  int fr = lane & 15, ko = (lane >> 4) << 3;

  f32x4 acc[4][4] = {};

  int srow[2], scol[2];
  for (int i = 0; i < 2; ++i) {
    int off = (wv << 11) + (i << 10) + (lane << 4);
    srow[i] = off >> 6;           // 64B per row (32 bf16)
    scol[i] = (off & 63) >> 1;    // element col within row
  }

  for (int kt = 0; kt < GK / 32; ++kt) {
    int k0 = kt << 5;
    for (int i = 0; i < 2; ++i) {
      unsigned short* ldsA = sA + (wv << 10) + (i << 9);
      unsigned short* ldsB = sB + (wv << 10) + (i << 9);
      GLD_LDS16(A + (size_t)(m0 + srow[i]) * GK + k0 + scol[i], ldsA);
      GLD_LDS16(Bm + (size_t)(n0 + srow[i]) * GK + k0 + scol[i], ldsB);
    }
    __syncthreads();

    bf16x8 af[4], bfr[4];
#pragma unroll
    for (int i = 0; i < 4; ++i) {
      af[i]  = *(const bf16x8*)&sA[((wr << 6) + (i << 4) + fr) * 32 + ko];
      bfr[i] = *(const bf16x8*)&sB[((wc << 6) + (i << 4) + fr) * 32 + ko];
    }
#pragma unroll
    for (int m = 0; m < 4; ++m)
#pragma unroll
      for (int n = 0; n < 4; ++n)
        acc[m][n] = __builtin_amdgcn_mfma_f32_16x16x32_bf16(af[m], bfr[n],
                                                            acc[m][n], 0, 0, 0);
    __syncthreads();
  }

  // epilogue: C/D layout col=lane&15, row=(lane>>4)*4+j  [m89-verified]
  int r0 = (lane >> 4) << 2, c = lane & 15;
#pragma unroll
  for (int n = 0; n < 4; ++n) {
    int gcol = n0 + (wc << 6) + (n << 4) + c;
    float bv = bias[gcol];
#pragma unroll
    for (int m = 0; m < 4; ++m) {
      int gr = m0 + (wr << 6) + (m << 4) + r0;
#pragma unroll
      for (int j = 0; j < 4; ++j) {
        int grow = gr + j;                       // m index = b*4096 + s
        size_t o = ((size_t)(grow + (grow >> 12)) << 10) + gcol;
        out[o] = acc[m][n][j] + bv;
      }
    }
  }
}

// ---------------- cos scores: thread-per-key, no per-key reduce -------------
// Block = 256 threads = 256 keys. d tiled by 32; keys staged to LDS
// transposed [dd][key] with XOR bank swizzle (conflict-free write+read).
// q read wave-uniform from qT[d][16] (scalar/broadcast loads).
__global__ __launch_bounds__(256) void cos_scores(
    const float* __restrict__ keys,    // KK x DD
    const float* __restrict__ qT,      // DD x 16
    float* __restrict__ pscore,        // 16 x nblk
    int* __restrict__ pidx) {
  constexpr int DT = 32;
  __shared__ float kt[DT][256];        // 32 KB
  __shared__ float rs[4][16];
  __shared__ int   ri[4][16];

  int tid = threadIdx.x, lane = tid & 63, w = tid >> 6;
  int k0 = blockIdx.x * 256;

  float acc[16] = {0.f, 0.f, 0.f, 0.f, 0.f, 0.f, 0.f, 0.f,
                   0.f, 0.f, 0.f, 0.f, 0.f, 0.f, 0.f, 0.f};
  float nrm = 0.f;

  // staging assignment: instr i covers key rows i*32+(tid>>3), chunk (tid&7)*4
  int srow = tid >> 3, scol = (tid & 7) << 2;
  const float* gsrc = keys + (size_t)(k0 + srow) * DD + scol;

  float4 stg[8];
#pragma unroll
  for (int i = 0; i < 8; ++i)
    stg[i] = *(const float4*)(gsrc + (size_t)i * 32 * DD);

  for (int t = 0; t < DD / DT; ++t) {
    // write staged tile (waits vmcnt on stg implicitly)
#pragma unroll
    for (int i = 0; i < 8; ++i) {
      int r = (i << 5) + srow;
#pragma unroll
      for (int j = 0; j < 4; ++j) {
        int dd = scol + j;
        kt[dd][r ^ (((dd >> 2) & 7) << 2)] = stg[i][j];
      }
    }
    __syncthreads();

    // issue next tile's loads early (T14): latency hides under compute
    if (t + 1 < DD / DT) {
      int d0n = (t + 1) * DT;
#pragma unroll
      for (int i = 0; i < 8; ++i)
        stg[i] = *(const float4*)(gsrc + (size_t)i * 32 * DD + d0n);
    }

    const float* qrow = qT + t * DT * 16;
#pragma unroll
    for (int dd = 0; dd < DT; ++dd) {
      float kv = kt[dd][tid ^ (((dd >> 2) & 7) << 2)];
      float4 q0 = *(const float4*)(qrow + dd * 16 + 0);
      float4 q1 = *(const float4*)(qrow + dd * 16 + 4);
      float4 q2 = *(const float4*)(qrow + dd * 16 + 8);
      float4 q3 = *(const float4*)(qrow + dd * 16 + 12);
      acc[0] = fmaf(kv, q0.x, acc[0]);   acc[1] = fmaf(kv, q0.y, acc[1]);
      acc[2] = fmaf(kv, q0.z, acc[2]);   acc[3] = fmaf(kv, q0.w, acc[3]);
      acc[4] = fmaf(kv, q1.x, acc[4]);   acc[5] = fmaf(kv, q1.y, acc[5]);
      acc[6] = fmaf(kv, q1.z, acc[6]);   acc[7] = fmaf(kv, q1.w, acc[7]);
      acc[8] = fmaf(kv, q2.x, acc[8]);   acc[9] = fmaf(kv, q2.y, acc[9]);
      acc[10] = fmaf(kv, q2.z, acc[10]); acc[11] = fmaf(kv, q2.w, acc[11]);
      acc[12] = fmaf(kv, q3.x, acc[12]); acc[13] = fmaf(kv, q3.y, acc[13]);
      acc[14] = fmaf(kv, q3.z, acc[14]); acc[15] = fmaf(kv, q3.w, acc[15]);
      nrm = fmaf(kv, kv, nrm);
    }
    __syncthreads();
  }

  // per-thread scores; block-level partial argmax per batch
  float inv = rsqrtf(fmaxf(nrm, 1e-24f));
#pragma unroll
  for (int b = 0; b < 16; ++b) {
    float s = acc[b] * inv;
    int i = k0 + tid;
#pragma unroll
    for (int off = 32; off; off >>= 1) {
      float s2 = __shfl_xor(s, off);
      int i2 = __shfl_xor(i, off);
      if (s2 > s || (s2 == s && i2 < i)) { s = s2; i = i2; }
    }
    if (lane == 0) { rs[w][b] = s; ri[w][b] = i; }
  }
  __syncthreads();
  if (tid < 16) {
    float bs = rs[0][tid]; int bi = ri[0][tid];
#pragma unroll
    for (int w2 = 1; w2 < 4; ++w2) {
      float s = rs[w2][tid]; int i = ri[w2][tid];
      if (s > bs || (s == bs && i < bi)) { bs = s; bi = i; }
    }
    pscore[(size_t)tid * gridDim.x + blockIdx.x] = bs;
    pidx[(size_t)tid * gridDim.x + blockIdx.x] = bi;
  }
}

// ---------------- final argmax reduce + token gather + l2norm ---------------
__global__ __launch_bounds__(256) void select_write(
    const float* __restrict__ pscore, const int* __restrict__ pidx, int nb,
    const int* __restrict__ ktv, const float* __restrict__ values,
    float* __restrict__ out) {
  __shared__ float ss[4];
  __shared__ int si[4];
  __shared__ float snrm;
  __shared__ int swin;
  int b = blockIdx.x, tid = threadIdx.x, lane = tid & 63, wv = tid >> 6;

  float best = -1e30f;
  int bidx = 0x7fffffff;
  for (int t = tid; t < nb; t += 256) {
    float s = pscore[(size_t)b * nb + t];
    int i = pidx[(size_t)b * nb + t];
    if (s > best || (s == best && i < bidx)) { best = s; bidx = i; }
  }
#pragma unroll
  for (int off = 32; off; off >>= 1) {
    float s = __shfl_xor(best, off);
    int i = __shfl_xor(bidx, off);
    if (s > best || (s == best && i < bidx)) { best = s; bidx = i; }
  }
  if (lane == 0) { ss[wv] = best; si[wv] = bidx; }
  __syncthreads();
  if (tid == 0) {
    float bs = ss[0]; int bi = si[0];
    for (int w2 = 1; w2 < 4; ++w2)
      if (ss[w2] > bs || (ss[w2] == bs && si[w2] < bi)) { bs = ss[w2]; bi = si[w2]; }
    swin = ktv[bi];   // key_to_value mapping
  }
  __syncthreads();
  int idx = swin;

  float4 v = ((const float4*)(values + (size_t)idx * DD))[tid];
  float nrm = v.x * v.x + v.y * v.y + v.z * v.z + v.w * v.w;
#pragma unroll
  for (int off = 32; off; off >>= 1) nrm += __shfl_xor(nrm, off);
  if (lane == 0) ss[wv] = nrm;
  __syncthreads();
  if (tid == 0) snrm = rsqrtf(fmaxf(ss[0] + ss[1] + ss[2] + ss[3], 1e-24f));
  __syncthreads();
  float inv = snrm;

  float4 o;
  o.x = v.x * inv; o.y = v.y * inv; o.z = v.z * inv; o.w = v.w * inv;
  ((float4*)(out + (((size_t)b * (SS + 1) + SS) << 10)))[tid] = o;
}

// ---------------- launcher ---------------------------------------------------
extern "C" void kernel_launch(void* const* d_in, const int* in_sizes, int n_in,
                              void* d_out, int out_size, void* d_ws,
                              size_t ws_size, hipStream_t stream) {
  const float* hidden = (const float*)d_in[0];
  const float* csig   = (const float*)d_in[1];
  const float* keys   = (const float*)d_in[2];
  const float* values = (const float*)d_in[3];
  const int*   ktv    = (const int*)d_in[4];
  const float* W      = (const float*)d_in[5];
  const float* bias   = (const float*)d_in[6];
  float* out = (float*)d_out;

  char* ws = (char*)d_ws;
  unsigned short* hbf = (unsigned short*)ws;                          // 128 MB
  unsigned short* wbf = (unsigned short*)(ws + (size_t)GM * GK * 2);  // 2 MB
  char* p = ws + (size_t)GM * GK * 2 + (size_t)DD * GK * 2;
  float* pscore = (float*)p;                       // 16 x 256
  int* pidx = (int*)(p + 16 * 256 * sizeof(float));
  float* qT = (float*)(p + 2 * 16 * 256 * sizeof(float));  // 1024 x 16

  // 1) conversions + q transpose
  cvt_bf16<<<4096, 256, 0, stream>>>(hidden, hbf, GM * GK / 8);
  cvt_bf16<<<512, 256, 0, stream>>>(W, wbf, DD * GK / 8);
  qt_prep<<<64, 256, 0, stream>>>(csig, qT);

  // 2) cos-similarity scores + per-block partial argmax
  cos_scores<<<256, 256, 0, stream>>>(keys, qT, pscore, pidx);

  // 3) GEMM + bias into out rows s<4096
  gemm_bt<<<(GM / 128) * (DD / 128), 256, 0, stream>>>(hbf, wbf, bias, out);

  // 4) final reduce + token row s=4096
  select_write<<<BB, 256, 0, stream>>>(pscore, pidx, 256, ktv, values, out);
}

// Round 3
// 396.485 us; speedup vs baseline: 1.4190x; 1.1726x over previous
//
#include <hip/hip_runtime.h>

// Problem constants (fixed by setup_inputs)
constexpr int BB = 16;         // batch
constexpr int SS = 4096;       // seq
constexpr int DD = 1024;       // hidden dim
constexpr int KK = 65536;      // num keys
constexpr int GM = BB * SS;    // GEMM M = 65536
constexpr int GK = DD;         // GEMM K = 1024

typedef __attribute__((ext_vector_type(8))) short bf16x8;
typedef __attribute__((ext_vector_type(4))) float f32x4;
typedef __attribute__((ext_vector_type(8))) unsigned short ushort8;

#define GLD_LDS16(g, l)                                                        \
  __builtin_amdgcn_global_load_lds(                                            \
      (const __attribute__((address_space(1))) void*)(g),                      \
      (__attribute__((address_space(3))) void*)(l), 16, 0, 0)

__device__ __forceinline__ unsigned short f2bf(float x) {
  unsigned u = __float_as_uint(x);
  u += 0x7fffu + ((u >> 16) & 1u);   // RNE
  return (unsigned short)(u >> 16);
}

// ---------------- fp32 -> bf16 conversion (8 elems/thread/iter) -------------
__global__ void cvt_bf16(const float* __restrict__ in,
                         unsigned short* __restrict__ out, int n8) {
  int stride = gridDim.x * blockDim.x;
  for (int i = blockIdx.x * blockDim.x + threadIdx.x; i < n8; i += stride) {
    const float4* p = (const float4*)in + (size_t)i * 2;
    float4 a = p[0], b = p[1];
    ushort8 r;
    r[0] = f2bf(a.x); r[1] = f2bf(a.y); r[2] = f2bf(a.z); r[3] = f2bf(a.w);
    r[4] = f2bf(b.x); r[5] = f2bf(b.y); r[6] = f2bf(b.z); r[7] = f2bf(b.w);
    *(ushort8*)(out + (size_t)i * 8) = r;
  }
}

// ---------------- q transpose: csig[16][1024] -> qT[1024][16] ---------------
__global__ __launch_bounds__(256) void qt_prep(const float* __restrict__ csig,
                                               float* __restrict__ qT) {
  int e = blockIdx.x * 256 + threadIdx.x;   // 64 blocks cover 16384
  int b = e >> 10, d = e & 1023;
  qT[d * 16 + b] = csig[e];
}

// =====================  GEMM: 256x256 tile, 8-phase schedule ================
// C[m,n] = sum_k A[m,k]*W[n,k] + bias[n].  BM=BN=256, BK=64, 8 waves (2Mx4N),
// LDS 128 KiB (2 buf x (A 32KB + B 32KB)).  K = 1024 -> 16 K-tiles, 8 iters.
// Stage schedule (quarter granularity, 2 gload_lds/thread/phase):
//   ph1: T+1{Aq1,Aq3}  ph2: T+2{Aq0,Aq2}  ph3: T+2{Bq0,Bq1} ph4: T+2{Bq2,Bq3}
//   ph5: T+2{Aq1,Aq3}  ph6: T+3{Aq0,Aq2}  ph7: T+3{Bq0,Bq1} ph8: T+3{Bq2,Bq3}
// vmcnt(6) at ph4/ph8 forces all but the last 3 phases' stages -> next tile
// fully landed before its first read.  Regions staged are exactly those whose
// reads completed >=1 phase earlier (Q0 reads A-half lo + B lo, Q1 B hi,
// Q2 A-half hi, Q3 none; B frags stay in registers).
// LDS swizzle: short_idx ^= (row&7)<<3 (conflict-free b128 reads), applied as
// inverse-permuted GLOBAL source + swizzled ds_read (both-sides rule).

#define LDA8(AH, BUF) do {                                                     \
  _Pragma("unroll") for (int ms = 0; ms < 4; ++ms) {                           \
    int rowa = (wm << 7) + ((AH) << 6) + (ms << 4) + fr;                       \
    _Pragma("unroll") for (int ks = 0; ks < 2; ++ks) {                         \
      int ia = ((rowa << 6) + (ks << 5) + (kg << 3)) ^ sw;                     \
      ar[ms * 2 + ks] = *(const bf16x8*)&lds[(BUF) + ia]; } }                  \
} while (0)

#define LDB4(NP, BUF) do {                                                     \
  _Pragma("unroll") for (int nn = 0; nn < 2; ++nn) {                           \
    int rowb = (wn << 6) + ((((NP) << 1) + nn) << 4) + fr;                     \
    _Pragma("unroll") for (int ks = 0; ks < 2; ++ks) {                         \
      int ib = ((rowb << 6) + (ks << 5) + (kg << 3)) ^ sw;                     \
      br[(((NP) << 1) + nn) * 2 + ks] = *(const bf16x8*)&lds[(BUF) + ib]; } }  \
} while (0)

#define MFMAQ(AH, NP) do {                                                     \
  _Pragma("unroll") for (int ms = 0; ms < 4; ++ms)                             \
  _Pragma("unroll") for (int nn = 0; nn < 2; ++nn)                             \
  _Pragma("unroll") for (int ks = 0; ks < 2; ++ks)                             \
    acc[((AH) << 2) + ms][((NP) << 1) + nn] =                                  \
      __builtin_amdgcn_mfma_f32_16x16x32_bf16(ar[ms * 2 + ks],                 \
        br[(((NP) << 1) + nn) * 2 + ks],                                       \
        acc[((AH) << 2) + ms][((NP) << 1) + nn], 0, 0, 0);                     \
} while (0)

#define STAGEQ(GB, LB, QJ)                                                     \
  GLD_LDS16((GB) + (size_t)(((QJ) << 6) + srq) * GK + ssc,                     \
            &lds[(LB) + ((((QJ) << 9) + (wv << 6)) << 3)])

#define PH_MID do { __builtin_amdgcn_s_barrier();                              \
  asm volatile("s_waitcnt lgkmcnt(0)" ::: "memory");                           \
  __builtin_amdgcn_sched_barrier(0);                                           \
  __builtin_amdgcn_s_setprio(1); } while (0)

#define PH_END do { __builtin_amdgcn_s_setprio(0);                             \
  __builtin_amdgcn_s_barrier(); } while (0)

#define PH_END_V(N) do { __builtin_amdgcn_s_setprio(0);                        \
  asm volatile("s_waitcnt vmcnt(" #N ")" ::: "memory");                        \
  __builtin_amdgcn_sched_barrier(0);                                           \
  __builtin_amdgcn_s_barrier(); } while (0)

__global__ __launch_bounds__(512, 2) void gemm8(
    const unsigned short* __restrict__ A,   // GM x GK bf16
    const unsigned short* __restrict__ Bm,  // DD x GK bf16 (W row-major)
    const float* __restrict__ bias,         // DD fp32
    float* __restrict__ out) {
  __shared__ unsigned short lds[65536];     // 128 KiB

  // bijective XCD swizzle: 1024 wgs, 8 XCDs -> 128 contiguous per XCD
  int g = blockIdx.x;
  int t = ((g & 7) << 7) + (g >> 3);
  int mt = t >> 2, nt = t & 3;              // 256 M-tiles x 4 N-tiles
  int m0 = mt << 8, n0 = nt << 8;

  int tid = threadIdx.x, lane = tid & 63, wv = tid >> 6;
  int wm = wv >> 2, wn = wv & 3;            // 2M x 4N waves, each owns 128x64
  int fr = lane & 15, kg = lane >> 4;
  int sw = (fr & 7) << 3;                   // read-side swizzle (short idx)

  int srq = (wv << 3) + (lane >> 3);        // staging row within quarter
  int ssc = (((lane & 7) ^ ((lane >> 3) & 7)) << 3);  // pre-swizzled src col

  const unsigned short* Ag = A + (size_t)m0 * GK;
  const unsigned short* Bg = Bm + (size_t)n0 * GK;

  f32x4 acc[8][4] = {};
  bf16x8 ar[8], br[8];

  // ---- prologue: tile0 (8q) + tile1 {Aq0,Aq2,Bq0-3}; force tile0 ----
  {
    const unsigned short* b0 = Bg;
    const unsigned short* a1 = Ag + 64;
    const unsigned short* b1 = Bg + 64;
    STAGEQ(Ag, 0, 0); STAGEQ(Ag, 0, 1); STAGEQ(Ag, 0, 2); STAGEQ(Ag, 0, 3);
    STAGEQ(b0, 16384, 0); STAGEQ(b0, 16384, 1);
    STAGEQ(b0, 16384, 2); STAGEQ(b0, 16384, 3);
    STAGEQ(a1, 32768, 0); STAGEQ(a1, 32768, 2);
    STAGEQ(b1, 49152, 0); STAGEQ(b1, 49152, 1);
    STAGEQ(b1, 49152, 2); STAGEQ(b1, 49152, 3);
    asm volatile("s_waitcnt vmcnt(6)" ::: "memory");
    __builtin_amdgcn_sched_barrier(0);
    __builtin_amdgcn_s_barrier();
  }

  for (int i = 0; i < 7; ++i) {
    const unsigned short* a1 = Ag + (size_t)(2 * i + 1) * 64;
    const unsigned short* a2 = Ag + (size_t)(2 * i + 2) * 64;
    const unsigned short* b2 = Bg + (size_t)(2 * i + 2) * 64;
    const unsigned short* a3 = Ag + (size_t)(2 * i + 3) * 64;
    const unsigned short* b3 = Bg + (size_t)(2 * i + 3) * 64;
    // ph1: Q0 of tile 2i (buf0)
    LDA8(0, 0); LDB4(0, 16384);
    STAGEQ(a1, 32768, 1); STAGEQ(a1, 32768, 3);
    PH_MID; MFMAQ(0, 0); PH_END;
    // ph2: Q1
    LDB4(1, 16384);
    STAGEQ(a2, 0, 0); STAGEQ(a2, 0, 2);
    PH_MID; MFMAQ(0, 1); PH_END;
    // ph3: Q2
    LDA8(1, 0);
    STAGEQ(b2, 16384, 0); STAGEQ(b2, 16384, 1);
    PH_MID; MFMAQ(1, 0); PH_END;
    // ph4: Q3 (+vmcnt: forces tile 2i+1 complete)
    STAGEQ(b2, 16384, 2); STAGEQ(b2, 16384, 3);
    PH_MID; MFMAQ(1, 1); PH_END_V(6);
    // ph5: Q0 of tile 2i+1 (buf1)
    LDA8(0, 32768); LDB4(0, 49152);
    STAGEQ(a2, 0, 1); STAGEQ(a2, 0, 3);
    PH_MID; MFMAQ(0, 0); PH_END;
    // ph6: Q1
    LDB4(1, 49152);
    STAGEQ(a3, 32768, 0); STAGEQ(a3, 32768, 2);
    PH_MID; MFMAQ(0, 1); PH_END;
    // ph7: Q2
    LDA8(1, 32768);
    STAGEQ(b3, 49152, 0); STAGEQ(b3, 49152, 1);
    PH_MID; MFMAQ(1, 0); PH_END;
    // ph8: Q3 (+vmcnt: forces tile 2i+2 complete)
    STAGEQ(b3, 49152, 2); STAGEQ(b3, 49152, 3);
    PH_MID; MFMAQ(1, 1); PH_END_V(6);
  }

  // ---- peeled final iteration: tiles 14 (buf0), 15 (buf1) ----
  {
    const unsigned short* a15 = Ag + (size_t)15 * 64;
    LDA8(0, 0); LDB4(0, 16384);
    STAGEQ(a15, 32768, 1); STAGEQ(a15, 32768, 3);
    PH_MID; MFMAQ(0, 0); PH_END;
    LDB4(1, 16384); PH_MID; MFMAQ(0, 1); PH_END;
    LDA8(1, 0);     PH_MID; MFMAQ(1, 0); PH_END;
    PH_MID; MFMAQ(1, 1); PH_END_V(0);
    LDA8(0, 32768); LDB4(0, 49152); PH_MID; MFMAQ(0, 0); PH_END;
    LDB4(1, 49152); PH_MID; MFMAQ(0, 1); PH_END;
    LDA8(1, 32768); PH_MID; MFMAQ(1, 0); PH_END;
    PH_MID; MFMAQ(1, 1);
    __builtin_amdgcn_s_setprio(0);
  }

  // ---- epilogue: C/D layout col=lane&15, row=(lane>>4)*4+j ----
  int r0 = kg << 2, cc = fr;
#pragma unroll
  for (int ni = 0; ni < 4; ++ni) {
    int gcol = n0 + (wn << 6) + (ni << 4) + cc;
    float bv = bias[gcol];
#pragma unroll
    for (int mi = 0; mi < 8; ++mi) {
      int gr = m0 + (wm << 7) + (mi << 4) + r0;
#pragma unroll
      for (int j = 0; j < 4; ++j) {
        int grow = gr + j;                       // m index = b*4096 + s
        size_t o = ((size_t)(grow + (grow >> 12)) << 10) + gcol;
        out[o] = acc[mi][ni][j] + bv;
      }
    }
  }
}

// ---------------- cos partial dots: thread-per-key, d-split x4 --------------
// Block (kg, dc): keys [kg*256, +256), d in [dc*256, +256).  q chunk in LDS
// (broadcast ds_reads).  Keys staged transposed [dd][key] with XOR swizzle.
__global__ __launch_bounds__(256) void cos_part4(
    const float* __restrict__ keys,    // KK x DD
    const float* __restrict__ qT,      // DD x 16
    float* __restrict__ pd,            // [4][KK][16]
    float* __restrict__ pn) {          // [4][KK]
  __shared__ float kt[32][256];        // 32 KB
  __shared__ float qs[256 * 16];       // 16 KB

  int tid = threadIdx.x;
  int kgrp = blockIdx.x & 255, dc = blockIdx.x >> 8;
  int k0 = kgrp << 8, d0 = dc << 8;

  // stage q chunk qT[d0..d0+256)[16] -> qs
  {
    const float4* src = (const float4*)(qT + (size_t)d0 * 16);
    float4* dst = (float4*)qs;
#pragma unroll
    for (int i = 0; i < 4; ++i) dst[tid + i * 256] = src[tid + i * 256];
  }

  float acc[16] = {0.f, 0.f, 0.f, 0.f, 0.f, 0.f, 0.f, 0.f,
                   0.f, 0.f, 0.f, 0.f, 0.f, 0.f, 0.f, 0.f};
  float nrm = 0.f;

  int srow = tid >> 3, scol = (tid & 7) << 2;
  const float* gsrc = keys + (size_t)(k0 + srow) * DD + d0 + scol;

  float4 stg[8];
#pragma unroll
  for (int i = 0; i < 8; ++i)
    stg[i] = *(const float4*)(gsrc + (size_t)i * 32 * DD);

  for (int t = 0; t < 8; ++t) {
#pragma unroll
    for (int i = 0; i < 8; ++i) {
      int r = (i << 5) + srow;
#pragma unroll
      for (int j = 0; j < 4; ++j) {
        int dd = scol + j;
        kt[dd][r ^ (((dd >> 2) & 7) << 2)] = stg[i][j];
      }
    }
    __syncthreads();    // kt (and, at t=0, qs) visible

    if (t + 1 < 8) {    // issue next tile early (T14)
#pragma unroll
      for (int i = 0; i < 8; ++i)
        stg[i] = *(const float4*)(gsrc + (size_t)i * 32 * DD + (t + 1) * 32);
    }

    const float* qb = qs + (t << 5) * 16;
#pragma unroll
    for (int dd = 0; dd < 32; ++dd) {
      float kv = kt[dd][tid ^ (((dd >> 2) & 7) << 2)];
      float4 q0 = *(const float4*)(qb + dd * 16 + 0);
      float4 q1 = *(const float4*)(qb + dd * 16 + 4);
      float4 q2 = *(const float4*)(qb + dd * 16 + 8);
      float4 q3 = *(const float4*)(qb + dd * 16 + 12);
      acc[0]  = fmaf(kv, q0.x, acc[0]);  acc[1]  = fmaf(kv, q0.y, acc[1]);
      acc[2]  = fmaf(kv, q0.z, acc[2]);  acc[3]  = fmaf(kv, q0.w, acc[3]);
      acc[4]  = fmaf(kv, q1.x, acc[4]);  acc[5]  = fmaf(kv, q1.y, acc[5]);
      acc[6]  = fmaf(kv, q1.z, acc[6]);  acc[7]  = fmaf(kv, q1.w, acc[7]);
      acc[8]  = fmaf(kv, q2.x, acc[8]);  acc[9]  = fmaf(kv, q2.y, acc[9]);
      acc[10] = fmaf(kv, q2.z, acc[10]); acc[11] = fmaf(kv, q2.w, acc[11]);
      acc[12] = fmaf(kv, q3.x, acc[12]); acc[13] = fmaf(kv, q3.y, acc[13]);
      acc[14] = fmaf(kv, q3.z, acc[14]); acc[15] = fmaf(kv, q3.w, acc[15]);
      nrm = fmaf(kv, kv, nrm);
    }
    __syncthreads();    // reads done before next tile's writes
  }

  int k = k0 + tid;
  float4* po = (float4*)(pd + ((size_t)dc * KK + k) * 16);
  po[0] = make_float4(acc[0], acc[1], acc[2], acc[3]);
  po[1] = make_float4(acc[4], acc[5], acc[6], acc[7]);
  po[2] = make_float4(acc[8], acc[9], acc[10], acc[11]);
  po[3] = make_float4(acc[12], acc[13], acc[14], acc[15]);
  pn[(size_t)dc * KK + k] = nrm;
}

// ---------------- combine partials -> cos -> per-block argmax ---------------
__global__ __launch_bounds__(256) void cos_combine(
    const float* __restrict__ pd, const float* __restrict__ pn,
    float* __restrict__ pscore, int* __restrict__ pidx) {
  __shared__ float rs[4][16];
  __shared__ int ri[4][16];
  int tid = threadIdx.x, lane = tid & 63, w = tid >> 6;
  int k = blockIdx.x * 256 + tid;

  float d[16] = {0.f, 0.f, 0.f, 0.f, 0.f, 0.f, 0.f, 0.f,
                 0.f, 0.f, 0.f, 0.f, 0.f, 0.f, 0.f, 0.f};
  float nrm = 0.f;
#pragma unroll
  for (int dc = 0; dc < 4; ++dc) {
    const float4* p = (const float4*)(pd + ((size_t)dc * KK + k) * 16);
#pragma unroll
    for (int i = 0; i < 4; ++i) {
      float4 v = p[i];
      d[i * 4 + 0] += v.x; d[i * 4 + 1] += v.y;
      d[i * 4 + 2] += v.z; d[i * 4 + 3] += v.w;
    }
    nrm += pn[(size_t)dc * KK + k];
  }
  float inv = rsqrtf(fmaxf(nrm, 1e-24f));

#pragma unroll
  for (int b = 0; b < 16; ++b) {
    float s = d[b] * inv;
    int i = k;
#pragma unroll
    for (int off = 32; off; off >>= 1) {
      float s2 = __shfl_xor(s, off);
      int i2 = __shfl_xor(i, off);
      if (s2 > s || (s2 == s && i2 < i)) { s = s2; i = i2; }
    }
    if (lane == 0) { rs[w][b] = s; ri[w][b] = i; }
  }
  __syncthreads();
  if (tid < 16) {
    float bs = rs[0][tid]; int bi = ri[0][tid];
#pragma unroll
    for (int w2 = 1; w2 < 4; ++w2) {
      float s = rs[w2][tid]; int i = ri[w2][tid];
      if (s > bs || (s == bs && i < bi)) { bs = s; bi = i; }
    }
    pscore[(size_t)tid * gridDim.x + blockIdx.x] = bs;
    pidx[(size_t)tid * gridDim.x + blockIdx.x] = bi;
  }
}

// ---------------- final argmax reduce + token gather + l2norm ---------------
__global__ __launch_bounds__(256) void select_write(
    const float* __restrict__ pscore, const int* __restrict__ pidx, int nb,
    const int* __restrict__ ktv, const float* __restrict__ values,
    float* __restrict__ out) {
  __shared__ float ss[4];
  __shared__ int si[4];
  __shared__ float snrm;
  __shared__ int swin;
  int b = blockIdx.x, tid = threadIdx.x, lane = tid & 63, wv = tid >> 6;

  float best = -1e30f;
  int bidx = 0x7fffffff;
  for (int t = tid; t < nb; t += 256) {
    float s = pscore[(size_t)b * nb + t];
    int i = pidx[(size_t)b * nb + t];
    if (s > best || (s == best && i < bidx)) { best = s; bidx = i; }
  }
#pragma unroll
  for (int off = 32; off; off >>= 1) {
    float s = __shfl_xor(best, off);
    int i = __shfl_xor(bidx, off);
    if (s > best || (s == best && i < bidx)) { best = s; bidx = i; }
  }
  if (lane == 0) { ss[wv] = best; si[wv] = bidx; }
  __syncthreads();
  if (tid == 0) {
    float bs = ss[0]; int bi = si[0];
    for (int w2 = 1; w2 < 4; ++w2)
      if (ss[w2] > bs || (ss[w2] == bs && si[w2] < bi)) { bs = ss[w2]; bi = si[w2]; }
    swin = ktv[bi];   // key_to_value mapping
  }
  __syncthreads();
  int idx = swin;

  float4 v = ((const float4*)(values + (size_t)idx * DD))[tid];
  float nrm = v.x * v.x + v.y * v.y + v.z * v.z + v.w * v.w;
#pragma unroll
  for (int off = 32; off; off >>= 1) nrm += __shfl_xor(nrm, off);
  if (lane == 0) ss[wv] = nrm;
  __syncthreads();
  if (tid == 0) snrm = rsqrtf(fmaxf(ss[0] + ss[1] + ss[2] + ss[3], 1e-24f));
  __syncthreads();
  float inv = snrm;

  float4 o;
  o.x = v.x * inv; o.y = v.y * inv; o.z = v.z * inv; o.w = v.w * inv;
  ((float4*)(out + (((size_t)b * (SS + 1) + SS) << 10)))[tid] = o;
}

// ---------------- launcher ---------------------------------------------------
extern "C" void kernel_launch(void* const* d_in, const int* in_sizes, int n_in,
                              void* d_out, int out_size, void* d_ws,
                              size_t ws_size, hipStream_t stream) {
  const float* hidden = (const float*)d_in[0];
  const float* csig   = (const float*)d_in[1];
  const float* keys   = (const float*)d_in[2];
  const float* values = (const float*)d_in[3];
  const int*   ktv    = (const int*)d_in[4];
  const float* W      = (const float*)d_in[5];
  const float* bias   = (const float*)d_in[6];
  float* out = (float*)d_out;

  char* ws = (char*)d_ws;
  size_t off = 0;
  unsigned short* hbf = (unsigned short*)(ws + off); off += (size_t)GM * GK * 2;
  unsigned short* wbf = (unsigned short*)(ws + off); off += (size_t)DD * GK * 2;
  float* pd     = (float*)(ws + off); off += (size_t)4 * KK * 16 * 4;
  float* pn     = (float*)(ws + off); off += (size_t)4 * KK * 4;
  float* pscore = (float*)(ws + off); off += (size_t)16 * 256 * 4;
  int*   pidx   = (int*)(ws + off);   off += (size_t)16 * 256 * 4;
  float* qT     = (float*)(ws + off); off += (size_t)DD * 16 * 4;

  // 1) conversions + q transpose
  cvt_bf16<<<4096, 256, 0, stream>>>(hidden, hbf, GM * GK / 8);
  cvt_bf16<<<512, 256, 0, stream>>>(W, wbf, DD * GK / 8);
  qt_prep<<<64, 256, 0, stream>>>(csig, qT);

  // 2) cos-similarity: partial dots (d-split x4) + combine/argmax
  cos_part4<<<1024, 256, 0, stream>>>(keys, qT, pd, pn);
  cos_combine<<<256, 256, 0, stream>>>(pd, pn, pscore, pidx);

  // 3) GEMM + bias into out rows s<4096 (256^2 8-phase)
  gemm8<<<1024, 512, 0, stream>>>(hbf, wbf, bias, out);

  // 4) final reduce + token row s=4096
  select_write<<<BB, 256, 0, stream>>>(pscore, pidx, 256, ktv, values, out);
}